// Round 6
// baseline (2127.305 us; speedup 1.0000x reference)
//
#include <hip/hip_runtime.h>
#include <math.h>

#define B_N 32768
#define U_N 256
#define H_N 1024
#define LR_C 0.01f
#define EPS_C 1e-3f

typedef unsigned short ushort_t;
typedef unsigned int uint_t;
using frag8 = __attribute__((ext_vector_type(8))) short;   // 8 bf16 = 4 VGPR
using f32x4 = __attribute__((ext_vector_type(4))) float;   // MFMA acc

__device__ __forceinline__ float gelu_f(float x) {
    return 0.5f * x * (1.0f + erff(x * 0.7071067811865475f));
}
__device__ __forceinline__ float dgelu_f(float x) {
    float c = 0.5f * (1.0f + erff(x * 0.7071067811865475f));
    float p = 0.3989422804014327f * expf(-0.5f * x * x);
    return c + x * p;
}

// fp32 -> (hi, lo) bf16 pair. hi = truncation (residual exact), lo = RNE(residual).
__device__ __forceinline__ void splitf(float v, ushort_t& h, ushort_t& l) {
    uint_t u = __float_as_uint(v);
    h = (ushort_t)(u >> 16);
    float r = v - __uint_as_float(u & 0xFFFF0000u);
    uint_t ru = __float_as_uint(r);
    l = (ushort_t)((ru + 0x7FFFu + ((ru >> 16) & 1u)) >> 16);
}
// fp32 -> bf16 RNE
__device__ __forceinline__ ushort_t cvt_rne(float v) {
    uint_t u = __float_as_uint(v);
    return (ushort_t)((u + 0x7FFFu + ((u >> 16) & 1u)) >> 16);
}

#define EPI_NONE 0
#define EPI_GELU 1
#define EPI_DGELU 2
#define EPI_ADDS 3

// ---------------------------------------------------------------------------
// MFMA GEMM: C[M,N] = epi( A[M,K] @ B[K,N] + bias ), B given as BT = B^T [N,K]
// pre-split bf16 planes. PASSES=3: split-bf16 (fp32-class). PASSES=1: plain bf16.
// ---------------------------------------------------------------------------
template<int ACONCAT, int AGELU, int EPI, int PASSES>
__global__ __launch_bounds__(256)
void mgemm_k(const float* A, const float* A2,
             const ushort_t* __restrict__ BTh, const ushort_t* __restrict__ BTl,
             const float* __restrict__ bias, const float* X, float* C,
             int M, int N, int K)
{
    __shared__ ushort_t Ah[128 * 40];
    __shared__ ushort_t Bh[128 * 40];
    __shared__ ushort_t Al[(PASSES == 3) ? 128 * 40 : 8];
    __shared__ ushort_t Bl[(PASSES == 3) ? 128 * 40 : 8];
    const int tid = threadIdx.x;
    const int m0 = blockIdx.x * 128, n0 = blockIdx.y * 128;
    const int lane = tid & 63, w = tid >> 6;
    const int wm = (w & 1) * 64, wn = (w >> 1) * 64;
    const int fr = lane & 15, fq = lane >> 4;
    const int sr = tid >> 1;
    const int sk = (tid & 1) * 16;

    f32x4 acc[4][4];
    #pragma unroll
    for (int i = 0; i < 4; i++)
        #pragma unroll
        for (int j = 0; j < 4; j++) acc[i][j] = (f32x4){0.f, 0.f, 0.f, 0.f};

    for (int k0 = 0; k0 < K; k0 += 32) {
        #pragma unroll
        for (int g = 0; g < 2; g++) {
            uint4 qh, qa;
            uint_t ph[4], pl[4];
            #pragma unroll
            for (int c = 0; c < 2; c++) {
                const int ak = k0 + sk + g * 8 + c * 4;
                const float* ap;
                if (ACONCAT) ap = (ak < 256) ? (A + (size_t)(m0 + sr) * 256 + ak)
                                             : (A2 + (size_t)(m0 + sr) * 256 + (ak - 256));
                else         ap = A + (size_t)(m0 + sr) * K + ak;
                float4 v = *(const float4*)ap;
                if (AGELU) { v.x = gelu_f(v.x); v.y = gelu_f(v.y);
                             v.z = gelu_f(v.z); v.w = gelu_f(v.w); }
                if (PASSES == 3) {
                    ushort_t h0,h1,h2,h3,l0,l1,l2,l3;
                    splitf(v.x,h0,l0); splitf(v.y,h1,l1); splitf(v.z,h2,l2); splitf(v.w,h3,l3);
                    ph[c*2]   = (uint_t)h0 | ((uint_t)h1 << 16);
                    ph[c*2+1] = (uint_t)h2 | ((uint_t)h3 << 16);
                    pl[c*2]   = (uint_t)l0 | ((uint_t)l1 << 16);
                    pl[c*2+1] = (uint_t)l2 | ((uint_t)l3 << 16);
                } else {
                    ph[c*2]   = (uint_t)cvt_rne(v.x) | ((uint_t)cvt_rne(v.y) << 16);
                    ph[c*2+1] = (uint_t)cvt_rne(v.z) | ((uint_t)cvt_rne(v.w) << 16);
                }
            }
            qh.x = ph[0]; qh.y = ph[1]; qh.z = ph[2]; qh.w = ph[3];
            *(uint4*)&Ah[sr * 40 + sk + g * 8] = qh;
            if (PASSES == 3) {
                qa.x = pl[0]; qa.y = pl[1]; qa.z = pl[2]; qa.w = pl[3];
                *(uint4*)&Al[sr * 40 + sk + g * 8] = qa;
            }
        }
        {
            const size_t bo = (size_t)(n0 + sr) * K + k0 + sk;
            *(uint4*)&Bh[sr * 40 + sk]     = *(const uint4*)&BTh[bo];
            *(uint4*)&Bh[sr * 40 + sk + 8] = *(const uint4*)&BTh[bo + 8];
            if (PASSES == 3) {
                *(uint4*)&Bl[sr * 40 + sk]     = *(const uint4*)&BTl[bo];
                *(uint4*)&Bl[sr * 40 + sk + 8] = *(const uint4*)&BTl[bo + 8];
            }
        }
        __syncthreads();

        frag8 afh[4], afl[4], bfh[4], bfl[4];
        #pragma unroll
        for (int i = 0; i < 4; i++) {
            const int ar = wm + i * 16 + fr;
            afh[i] = *(frag8*)&Ah[ar * 40 + fq * 8];
            if (PASSES == 3) afl[i] = *(frag8*)&Al[ar * 40 + fq * 8];
        }
        #pragma unroll
        for (int j = 0; j < 4; j++) {
            const int br = wn + j * 16 + fr;
            bfh[j] = *(frag8*)&Bh[br * 40 + fq * 8];
            if (PASSES == 3) bfl[j] = *(frag8*)&Bl[br * 40 + fq * 8];
        }
        #pragma unroll
        for (int i = 0; i < 4; i++)
            #pragma unroll
            for (int j = 0; j < 4; j++) {
                acc[i][j] = __builtin_amdgcn_mfma_f32_16x16x32_bf16(afh[i], bfh[j], acc[i][j], 0, 0, 0);
                if (PASSES == 3) {
                    acc[i][j] = __builtin_amdgcn_mfma_f32_16x16x32_bf16(afh[i], bfl[j], acc[i][j], 0, 0, 0);
                    acc[i][j] = __builtin_amdgcn_mfma_f32_16x16x32_bf16(afl[i], bfh[j], acc[i][j], 0, 0, 0);
                }
            }
        __syncthreads();
    }

    float bv[4] = {0.f, 0.f, 0.f, 0.f};
    if (bias != nullptr)
        #pragma unroll
        for (int j = 0; j < 4; j++) bv[j] = bias[n0 + wn + j * 16 + fr];
    #pragma unroll
    for (int i = 0; i < 4; i++)
        #pragma unroll
        for (int j = 0; j < 4; j++) {
            const int col = n0 + wn + j * 16 + fr;
            #pragma unroll
            for (int r = 0; r < 4; r++) {
                const int row = m0 + wm + i * 16 + fq * 4 + r;
                const size_t off = (size_t)row * N + col;
                float c = acc[i][j][r] + bv[j];
                if (EPI == EPI_GELU)       c = gelu_f(c);
                else if (EPI == EPI_DGELU) c = c * dgelu_f(X[off]);
                else if (EPI == EPI_ADDS)  c = c + 0.1f * X[off];
                C[off] = c;
            }
        }
}

// ---------------------------------------------------------------------------
// Weight-grad GEMM: C[M,N] += AT[M,K-chunk] @ (BTt[N,K-chunk])^T, both operands
// pre-transposed k-major bf16 (from t2t_k). Pure-copy staging, 1-pass, split-K.
// ---------------------------------------------------------------------------
__global__ __launch_bounds__(256)
void wgrad_k(const ushort_t* __restrict__ AT, const ushort_t* __restrict__ BTt,
             float* C, int M, int N, int K, int KC)
{
    __shared__ ushort_t Ah[128 * 40];
    __shared__ ushort_t Bh[128 * 40];
    const int tid = threadIdx.x;
    const int m0 = blockIdx.x * 128, n0 = blockIdx.y * 128;
    const int kbeg = blockIdx.z * KC;
    const int lane = tid & 63, w = tid >> 6;
    const int wm = (w & 1) * 64, wn = (w >> 1) * 64;
    const int fr = lane & 15, fq = lane >> 4;
    const int sr = tid >> 1;
    const int sk = (tid & 1) * 16;

    f32x4 acc[4][4];
    #pragma unroll
    for (int i = 0; i < 4; i++)
        #pragma unroll
        for (int j = 0; j < 4; j++) acc[i][j] = (f32x4){0.f, 0.f, 0.f, 0.f};

    for (int k0 = 0; k0 < KC; k0 += 32) {
        const size_t ao = (size_t)(m0 + sr) * K + kbeg + k0 + sk;
        *(uint4*)&Ah[sr * 40 + sk]     = *(const uint4*)&AT[ao];
        *(uint4*)&Ah[sr * 40 + sk + 8] = *(const uint4*)&AT[ao + 8];
        const size_t bo = (size_t)(n0 + sr) * K + kbeg + k0 + sk;
        *(uint4*)&Bh[sr * 40 + sk]     = *(const uint4*)&BTt[bo];
        *(uint4*)&Bh[sr * 40 + sk + 8] = *(const uint4*)&BTt[bo + 8];
        __syncthreads();

        frag8 af[4], bf[4];
        #pragma unroll
        for (int i = 0; i < 4; i++) af[i] = *(frag8*)&Ah[(wm + i * 16 + fr) * 40 + fq * 8];
        #pragma unroll
        for (int j = 0; j < 4; j++) bf[j] = *(frag8*)&Bh[(wn + j * 16 + fr) * 40 + fq * 8];
        #pragma unroll
        for (int i = 0; i < 4; i++)
            #pragma unroll
            for (int j = 0; j < 4; j++)
                acc[i][j] = __builtin_amdgcn_mfma_f32_16x16x32_bf16(af[i], bf[j], acc[i][j], 0, 0, 0);
        __syncthreads();
    }
    #pragma unroll
    for (int i = 0; i < 4; i++)
        #pragma unroll
        for (int j = 0; j < 4; j++) {
            const int col = n0 + wn + j * 16 + fr;
            #pragma unroll
            for (int r = 0; r < 4; r++) {
                const int row = m0 + wm + i * 16 + fq * 4 + r;
                atomicAdd(&C[(size_t)row * N + col], acc[i][j][r]);
            }
        }
}

// ---------------------------------------------------------------------------
// Transpose + bf16 convert: in fp32 [R,C] -> out bf16 [C,R]. Optional gelu.
// 64x64 LDS tile (+1 pad). Coalesced reads (4B x 64 lanes) and writes (8B x 16).
// ---------------------------------------------------------------------------
template<int GELU>
__global__ __launch_bounds__(256)
void t2t_k(const float* __restrict__ in, ushort_t* __restrict__ out, int R, int C)
{
    __shared__ float t[64][65];
    const int tid = threadIdx.x;
    const int R0 = blockIdx.x * 64, C0 = blockIdx.y * 64;
    const int c = tid & 63, rb = (tid >> 6) * 16;
    #pragma unroll
    for (int i = 0; i < 16; i++) {
        float v = in[(size_t)(R0 + rb + i) * C + C0 + c];
        if (GELU) v = gelu_f(v);
        t[rb + i][c] = v;
    }
    __syncthreads();
    const int orr = (tid & 15) * 4;      // output R offset (4 consecutive)
    const int oc0 = tid >> 4;            // 0..15
    #pragma unroll
    for (int j = 0; j < 4; j++) {
        const int oc = oc0 + j * 16;
        uint_t p0 = (uint_t)cvt_rne(t[orr + 0][oc]) | ((uint_t)cvt_rne(t[orr + 1][oc]) << 16);
        uint_t p1 = (uint_t)cvt_rne(t[orr + 2][oc]) | ((uint_t)cvt_rne(t[orr + 3][oc]) << 16);
        *(uint2*)&out[(size_t)(C0 + oc) * R + R0 + orr] = (uint2){p0, p1};
    }
}

// transpose + split: W [R,C] fp32 -> Th/Tl [C,R] bf16 planes
__global__ __launch_bounds__(256)
void tsplit_k(const float* __restrict__ W, ushort_t* __restrict__ Th,
              ushort_t* __restrict__ Tl, int R, int C)
{
    __shared__ float t[64][65];
    const int tid = threadIdx.x;
    const int R0 = blockIdx.x * 64, C0 = blockIdx.y * 64;
    const int c = tid & 63, rb = (tid >> 6) * 16;
    for (int i = 0; i < 16; i++)
        t[rb + i][c] = W[(size_t)(R0 + rb + i) * C + C0 + c];
    __syncthreads();
    const int orr = tid & 63, ob = (tid >> 6) * 16;
    for (int i = 0; i < 16; i++) {
        const int oc = ob + i;
        ushort_t h, l;
        splitf(t[orr][oc], h, l);
        Th[(size_t)(C0 + oc) * R + R0 + orr] = h;
        Tl[(size_t)(C0 + oc) * R + R0 + orr] = l;
    }
}

// transpose + SGD update + split: (W - LR*dW) [R,C] -> Th/Tl [C,R]
__global__ __launch_bounds__(256)
void tupd_k(const float* __restrict__ W, const float* __restrict__ dW,
            ushort_t* __restrict__ Th, ushort_t* __restrict__ Tl, int R, int C)
{
    __shared__ float t[64][65];
    const int tid = threadIdx.x;
    const int R0 = blockIdx.x * 64, C0 = blockIdx.y * 64;
    const int c = tid & 63, rb = (tid >> 6) * 16;
    for (int i = 0; i < 16; i++) {
        const size_t o = (size_t)(R0 + rb + i) * C + C0 + c;
        t[rb + i][c] = W[o] - LR_C * dW[o];
    }
    __syncthreads();
    const int orr = tid & 63, ob = (tid >> 6) * 16;
    for (int i = 0; i < 16; i++) {
        const int oc = ob + i;
        ushort_t h, l;
        splitf(t[orr][oc], h, l);
        Th[(size_t)(C0 + oc) * R + R0 + orr] = h;
        Tl[(size_t)(C0 + oc) * R + R0 + orr] = l;
    }
}

// elementwise split (no transpose)
__global__ __launch_bounds__(256)
void ssplit_k(const float* __restrict__ W, ushort_t* __restrict__ Th,
              ushort_t* __restrict__ Tl, int n4)
{
    const int i = blockIdx.x * 256 + threadIdx.x;
    if (i >= n4) return;
    float4 v = *(const float4*)(W + (size_t)i * 4);
    ushort_t h[4], l[4];
    splitf(v.x, h[0], l[0]); splitf(v.y, h[1], l[1]);
    splitf(v.z, h[2], l[2]); splitf(v.w, h[3], l[3]);
    uint2 ph, pl;
    ph.x = (uint_t)h[0] | ((uint_t)h[1] << 16); ph.y = (uint_t)h[2] | ((uint_t)h[3] << 16);
    pl.x = (uint_t)l[0] | ((uint_t)l[1] << 16); pl.y = (uint_t)l[2] | ((uint_t)l[3] << 16);
    *(uint2*)&Th[(size_t)i * 4] = ph;
    *(uint2*)&Tl[(size_t)i * 4] = pl;
}

__global__ __launch_bounds__(256)
void colsum_k(const float* __restrict__ A, float* out, int N, int rows)
{
    const int col = blockIdx.x * 256 + threadIdx.x;
    const int r0 = blockIdx.y * rows;
    float s = 0.f;
    for (int r = 0; r < rows; r++) s += A[(size_t)(r0 + r) * N + col];
    atomicAdd(&out[col], s);
}

// LayerNorm forward + dL/dr0 (row-wise; dr0 may alias r0)
__global__ __launch_bounds__(256)
void ln_fb_k(const float* r0, const float* __restrict__ phi,
             const float* __restrict__ gamma, const float* __restrict__ beta,
             float* recon, float* dr0)
{
    const int lane = threadIdx.x & 63;
    const int wv = threadIdx.x >> 6;
    const int row = blockIdx.x * 4 + wv;
    const size_t base = (size_t)row * U_N + (lane << 2);

    float4 xv = *(const float4*)(r0 + base);
    float s  = xv.x + xv.y + xv.z + xv.w;
    float sq = xv.x * xv.x + xv.y * xv.y + xv.z * xv.z + xv.w * xv.w;
    #pragma unroll
    for (int o = 32; o > 0; o >>= 1) { s += __shfl_xor(s, o); sq += __shfl_xor(sq, o); }
    const float m   = s * (1.0f / U_N);
    const float var = sq * (1.0f / U_N) - m * m;
    const float inv = rsqrtf(var + EPS_C);

    float4 gv = *(const float4*)(gamma + (lane << 2));
    float4 bv = *(const float4*)(beta + (lane << 2));
    float4 pv = *(const float4*)(phi + base);
    float xs[4] = {xv.x, xv.y, xv.z, xv.w};
    float gs[4] = {gv.x, gv.y, gv.z, gv.w};
    float bs[4] = {bv.x, bv.y, bv.z, bv.w};
    float ps[4] = {pv.x, pv.y, pv.z, pv.w};
    float rh[4], dh[4], rc[4];
    float s1 = 0.f, s2 = 0.f;
    const float gscale = 2.0f / ((float)B_N * (float)U_N);
    #pragma unroll
    for (int j = 0; j < 4; j++) {
        rh[j] = (xs[j] - m) * inv;
        rc[j] = rh[j] * gs[j] + bs[j];
        float g2 = gscale * (rc[j] - ps[j]);
        dh[j] = g2 * gs[j];
        s1 += dh[j];
        s2 += dh[j] * rh[j];
    }
    #pragma unroll
    for (int o = 32; o > 0; o >>= 1) { s1 += __shfl_xor(s1, o); s2 += __shfl_xor(s2, o); }
    const float mu1 = s1 * (1.0f / U_N);
    const float mu2 = s2 * (1.0f / U_N);
    float4 ov, dv;
    ov.x = rc[0]; ov.y = rc[1]; ov.z = rc[2]; ov.w = rc[3];
    dv.x = inv * (dh[0] - mu1 - rh[0] * mu2);
    dv.y = inv * (dh[1] - mu1 - rh[1] * mu2);
    dv.z = inv * (dh[2] - mu1 - rh[2] * mu2);
    dv.w = inv * (dh[3] - mu1 - rh[3] * mu2);
    *(float4*)(recon + base) = ov;
    *(float4*)(dr0 + base) = dv;
}

__global__ __launch_bounds__(256)
void bupd_k(const float* __restrict__ b1, const float* __restrict__ db1,
            const float* __restrict__ b2, const float* __restrict__ db2,
            float* __restrict__ b1u, float* __restrict__ b2u)
{
    const int i = blockIdx.x * 256 + threadIdx.x;
    if (i < H_N) b1u[i] = b1[i] - LR_C * db1[i];
    else if (i < H_N + U_N) b2u[i - H_N] = b2[i - H_N] - LR_C * db2[i - H_N];
}

extern "C" void kernel_launch(void* const* d_in, const int* in_sizes, int n_in,
                              void* d_out, int out_size, void* d_ws, size_t ws_size,
                              hipStream_t stream)
{
    const float* x      = (const float*)d_in[0];
    const float* h_prev = (const float*)d_in[1];
    const float* W_phi  = (const float*)d_in[2];
    const float* b_phi  = (const float*)d_in[3];
    const float* W_psi  = (const float*)d_in[4];
    const float* b_psi  = (const float*)d_in[5];
    const float* W1     = (const float*)d_in[6];
    const float* b1     = (const float*)d_in[7];
    const float* W2     = (const float*)d_in[8];
    const float* b2     = (const float*)d_in[9];
    const float* W_g    = (const float*)d_in[10];
    const float* g_bias = (const float*)d_in[11];
    const float* gamma  = (const float*)d_in[12];
    const float* beta   = (const float*)d_in[13];
    const float* W_h    = (const float*)d_in[14];
    const float* h_bias = (const float*)d_in[15];
    float* out = (float*)d_out;

    const size_t BU = (size_t)B_N * U_N;
    const size_t UH = (size_t)U_N * H_N;
    const size_t USHW = 2 * (2 * 131072 + 5 * 262144 + 3 * 65536); // weight planes (ushorts)

    // G-search with exact accounting: floats + weight planes + per-chunk transposed bf16
    int G = 1;
    while (G < 256) {
        size_t Bc_ = (size_t)B_N / G;
        size_t fl  = 2 * BU + Bc_ * (H_N + 3 * U_N) + 2 * UH + 2 * H_N + 2 * U_N;
        size_t ush = USHW + Bc_ * (2 * U_N + 2 * H_N);   // phiTc, deT, g1T, daT
        if (fl * 4 + ush * 2 + 64 <= ws_size) break;
        G *= 2;
    }
    const int Bc = B_N / G;
    const int KC = (Bc < 512) ? Bc : 512;   // wgrad split-K chunk
    const int Z  = Bc / KC;

    float* ws    = (float*)d_ws;
    float* phi   = ws;
    float* recon = phi   + BU;
    float* a1b   = recon + BU;                    // [Bc,H]: a1 -> da -> h2
    float* eb    = a1b   + (size_t)Bc * H_N;      // [Bc,U]: e -> feat
    float* r0b   = eb    + (size_t)Bc * U_N;      // [Bc,U]: r0 -> dr0 -> psi
    float* deb   = r0b   + (size_t)Bc * U_N;      // [Bc,U]
    float* dW1   = deb   + (size_t)Bc * U_N;      // [U,H]
    float* db1   = dW1 + UH;
    float* dW2   = db1 + H_N;                     // [H,U]
    float* db2   = dW2 + UH;
    float* b1u   = db2 + U_N;
    float* b2u   = b1u + H_N;
    ushort_t* us = (ushort_t*)(((uintptr_t)(b2u + U_N) + 15) & ~(uintptr_t)15);
    ushort_t* WphiT_h = us;                 ushort_t* WphiT_l = WphiT_h + 131072;
    ushort_t* WpsiT_h = WphiT_l + 131072;   ushort_t* WpsiT_l = WpsiT_h + 131072;
    ushort_t* W1T_h   = WpsiT_l + 131072;   ushort_t* W1T_l   = W1T_h + 262144;
    ushort_t* W2T_h   = W1T_l + 262144;     ushort_t* W2T_l   = W2T_h + 262144;
    ushort_t* W2s_h   = W2T_l + 262144;     ushort_t* W2s_l   = W2s_h + 262144;
    ushort_t* W1uT_h  = W2s_l + 262144;     ushort_t* W1uT_l  = W1uT_h + 262144;
    ushort_t* W2uT_h  = W1uT_l + 262144;    ushort_t* W2uT_l  = W2uT_h + 262144;
    ushort_t* WgT_h   = W2uT_l + 262144;    ushort_t* WgT_l   = WgT_h + 65536;
    ushort_t* Wgs_h   = WgT_l + 65536;      ushort_t* Wgs_l   = Wgs_h + 65536;
    ushort_t* WhT_h   = Wgs_l + 65536;      ushort_t* WhT_l   = WhT_h + 65536;
    // per-chunk transposed bf16 activations (k-major)
    ushort_t* phiTc = WhT_l + 65536;                    // [U, Bc]
    ushort_t* deT   = phiTc + (size_t)U_N * Bc;         // [U, Bc]
    ushort_t* g1T   = deT   + (size_t)U_N * Bc;         // [H, Bc]
    ushort_t* daT   = g1T   + (size_t)H_N * Bc;         // [H, Bc]

    hipMemsetAsync(dW1, 0, (2 * UH + H_N + U_N) * sizeof(float), stream);

    dim3 blk(256);
    tsplit_k<<<dim3(8, 4),  blk, 0, stream>>>(W_phi, WphiT_h, WphiT_l, 512, 256);
    tsplit_k<<<dim3(8, 4),  blk, 0, stream>>>(W_psi, WpsiT_h, WpsiT_l, 512, 256);
    tsplit_k<<<dim3(4, 16), blk, 0, stream>>>(W1, W1T_h, W1T_l, 256, 1024);
    tsplit_k<<<dim3(16, 4), blk, 0, stream>>>(W2, W2T_h, W2T_l, 1024, 256);
    tsplit_k<<<dim3(4, 4),  blk, 0, stream>>>(W_g, WgT_h, WgT_l, 256, 256);
    tsplit_k<<<dim3(4, 4),  blk, 0, stream>>>(W_h, WhT_h, WhT_l, 256, 256);
    ssplit_k<<<dim3(256),   blk, 0, stream>>>(W2, W2s_h, W2s_l, 65536);
    ssplit_k<<<dim3(64),    blk, 0, stream>>>(W_g, Wgs_h, Wgs_l, 16384);

    // phi = [x|h_prev] @ W_phi + b_phi
    mgemm_k<1,0,EPI_NONE,3><<<dim3(B_N/128, 2), blk, 0, stream>>>(
        x, h_prev, WphiT_h, WphiT_l, b_phi, nullptr, phi, B_N, U_N, 512);

    // Phase A: inner fwd+bwd, chunked
    for (int c = 0; c < G; c++) {
        const size_t off = (size_t)c * Bc;
        const float* phic = phi + off * U_N;
        // forward (3-pass)
        mgemm_k<0,0,EPI_NONE,3><<<dim3(Bc/128, 8), blk, 0, stream>>>(
            phic, nullptr, W1T_h, W1T_l, b1, nullptr, a1b, Bc, H_N, U_N);
        mgemm_k<0,1,EPI_NONE,3><<<dim3(Bc/128, 2), blk, 0, stream>>>(
            a1b, nullptr, W2T_h, W2T_l, b2, nullptr, eb, Bc, U_N, H_N);
        mgemm_k<0,0,EPI_NONE,3><<<dim3(Bc/128, 2), blk, 0, stream>>>(
            eb, nullptr, WgT_h, WgT_l, g_bias, nullptr, r0b, Bc, U_N, U_N);
        ln_fb_k<<<dim3(Bc/4), blk, 0, stream>>>(r0b, phic, gamma, beta, recon + off * U_N, r0b);
        // gradient path (1-pass bf16; error scaled by LR)
        mgemm_k<0,0,EPI_NONE,1><<<dim3(Bc/128, 2), blk, 0, stream>>>(
            r0b, nullptr, Wgs_h, Wgs_l, nullptr, nullptr, deb, Bc, U_N, U_N);
        // transposes -> k-major bf16 (must read a1b BEFORE da overwrites it)
        t2t_k<1><<<dim3(Bc/64, 16), blk, 0, stream>>>(a1b, g1T, Bc, H_N);   // gelu(a1)^T
        t2t_k<0><<<dim3(Bc/64, 4),  blk, 0, stream>>>(deb, deT, Bc, U_N);
        wgrad_k<<<dim3(8, 2, Z), blk, 0, stream>>>(g1T, deT, dW2, H_N, U_N, Bc, KC);
        colsum_k<<<dim3(1, Bc/128), blk, 0, stream>>>(deb, db2, U_N, 128);
        // da = (de @ W2^T) * dgelu(a1)  (in-place over a1b)
        mgemm_k<0,0,EPI_DGELU,1><<<dim3(Bc/128, 8), blk, 0, stream>>>(
            deb, nullptr, W2s_h, W2s_l, nullptr, a1b, a1b, Bc, H_N, U_N);
        t2t_k<0><<<dim3(Bc/64, 16), blk, 0, stream>>>(a1b, daT, Bc, H_N);
        t2t_k<0><<<dim3(Bc/64, 4),  blk, 0, stream>>>(phic, phiTc, Bc, U_N);
        wgrad_k<<<dim3(2, 8, Z), blk, 0, stream>>>(phiTc, daT, dW1, U_N, H_N, Bc, KC);
        colsum_k<<<dim3(4, Bc/128), blk, 0, stream>>>(a1b, db1, H_N, 128);
    }

    // Phase B: updated params (transposed + split)
    bupd_k<<<dim3(5), blk, 0, stream>>>(b1, db1, b2, db2, b1u, b2u);
    tupd_k<<<dim3(4, 16), blk, 0, stream>>>(W1, dW1, W1uT_h, W1uT_l, 256, 1024);
    tupd_k<<<dim3(16, 4), blk, 0, stream>>>(W2, dW2, W2uT_h, W2uT_l, 1024, 256);

    // Phase C
    for (int c = 0; c < G; c++) {
        const size_t off = (size_t)c * Bc;
        mgemm_k<1,0,EPI_NONE,3><<<dim3(Bc/128, 2), blk, 0, stream>>>(
            x + off * 256, h_prev + off * U_N, WpsiT_h, WpsiT_l, b_psi, nullptr, r0b, Bc, U_N, 512);
        mgemm_k<0,0,EPI_GELU,3><<<dim3(Bc/128, 8), blk, 0, stream>>>(
            r0b, nullptr, W1uT_h, W1uT_l, b1u, nullptr, a1b, Bc, H_N, U_N);
        mgemm_k<0,0,EPI_ADDS,3><<<dim3(Bc/128, 2), blk, 0, stream>>>(
            a1b, nullptr, W2uT_h, W2uT_l, b2u, recon + off * U_N, eb, Bc, U_N, H_N);
        mgemm_k<0,0,EPI_NONE,3><<<dim3(Bc/128, 2), blk, 0, stream>>>(
            eb, nullptr, WhT_h, WhT_l, h_bias, nullptr, out + off * U_N, Bc, U_N, U_N);
    }
}

// Round 7
// 968.105 us; speedup vs baseline: 2.1974x; 2.1974x over previous
//
#include <hip/hip_runtime.h>
#include <math.h>

#define B_N 32768
#define U_N 256
#define H_N 1024
#define LR_C 0.01f
#define EPS_C 1e-3f

typedef unsigned short ushort_t;
typedef unsigned int uint_t;
using frag8 = __attribute__((ext_vector_type(8))) short;   // 8 bf16 = 4 VGPR
using f32x4 = __attribute__((ext_vector_type(4))) float;   // MFMA acc

__device__ __forceinline__ float gelu_f(float x) {
    return 0.5f * x * (1.0f + erff(x * 0.7071067811865475f));
}
__device__ __forceinline__ float dgelu_f(float x) {
    float c = 0.5f * (1.0f + erff(x * 0.7071067811865475f));
    float p = 0.3989422804014327f * expf(-0.5f * x * x);
    return c + x * p;
}
__device__ __forceinline__ void splitf(float v, ushort_t& h, ushort_t& l) {
    uint_t u = __float_as_uint(v);
    h = (ushort_t)(u >> 16);
    float r = v - __uint_as_float(u & 0xFFFF0000u);
    uint_t ru = __float_as_uint(r);
    l = (ushort_t)((ru + 0x7FFFu + ((ru >> 16) & 1u)) >> 16);
}
__device__ __forceinline__ ushort_t cvt_rne(float v) {
    uint_t u = __float_as_uint(v);
    return (ushort_t)((u + 0x7FFFu + ((u >> 16) & 1u)) >> 16);
}
__device__ __forceinline__ float bf2f(ushort_t u) {
    return __uint_as_float((uint_t)u << 16);
}

#define EPI_NONE 0
#define EPI_GELU 1
#define EPI_ADDS 3

// bgemm epilogue modes
#define BEP_P   0   // bf16 row-major out
#define BEP_PT  1   // bf16 row-major + col-major [N,M]
#define BEP_A1  2   // g1=gelu rm + gp=dgelu rm + g1T ct
#define BEP_DAT 3   // acc * gp(bf16) -> col-major only

// ---------------------------------------------------------------------------
// 3-pass split-bf16 GEMM (fp32-class). Phase C only. A fp32 (optionally
// concat x|h2), BT pre-split bf16 [N,K] hi/lo. EPI_ADDS X is bf16 (recon).
// ---------------------------------------------------------------------------
template<int ACONCAT, int AGELU, int EPI>
__global__ __launch_bounds__(256)
void mgemm_k(const float* A, const float* A2,
             const ushort_t* __restrict__ BTh, const ushort_t* __restrict__ BTl,
             const float* __restrict__ bias, const ushort_t* __restrict__ Xr,
             float* C, int M, int N, int K)
{
    __shared__ ushort_t Ah[128 * 40], Al[128 * 40];
    __shared__ ushort_t Bh[128 * 40], Bl[128 * 40];
    const int tid = threadIdx.x;
    const int m0 = blockIdx.x * 128, n0 = blockIdx.y * 128;
    const int lane = tid & 63, w = tid >> 6;
    const int wm = (w & 1) * 64, wn = (w >> 1) * 64;
    const int fr = lane & 15, fq = lane >> 4;
    const int sr = tid >> 1;
    const int sk = (tid & 1) * 16;

    f32x4 acc[4][4];
    #pragma unroll
    for (int i = 0; i < 4; i++)
        #pragma unroll
        for (int j = 0; j < 4; j++) acc[i][j] = (f32x4){0.f, 0.f, 0.f, 0.f};

    for (int k0 = 0; k0 < K; k0 += 32) {
        #pragma unroll
        for (int g = 0; g < 2; g++) {
            uint4 qh, qa;
            uint_t ph[4], pl[4];
            #pragma unroll
            for (int c = 0; c < 2; c++) {
                const int ak = k0 + sk + g * 8 + c * 4;
                const float* ap;
                if (ACONCAT) ap = (ak < 256) ? (A + (size_t)(m0 + sr) * 256 + ak)
                                             : (A2 + (size_t)(m0 + sr) * 256 + (ak - 256));
                else         ap = A + (size_t)(m0 + sr) * K + ak;
                float4 v = *(const float4*)ap;
                if (AGELU) { v.x = gelu_f(v.x); v.y = gelu_f(v.y);
                             v.z = gelu_f(v.z); v.w = gelu_f(v.w); }
                ushort_t h0,h1,h2,h3,l0,l1,l2,l3;
                splitf(v.x,h0,l0); splitf(v.y,h1,l1); splitf(v.z,h2,l2); splitf(v.w,h3,l3);
                ph[c*2]   = (uint_t)h0 | ((uint_t)h1 << 16);
                ph[c*2+1] = (uint_t)h2 | ((uint_t)h3 << 16);
                pl[c*2]   = (uint_t)l0 | ((uint_t)l1 << 16);
                pl[c*2+1] = (uint_t)l2 | ((uint_t)l3 << 16);
            }
            qh.x = ph[0]; qh.y = ph[1]; qh.z = ph[2]; qh.w = ph[3];
            qa.x = pl[0]; qa.y = pl[1]; qa.z = pl[2]; qa.w = pl[3];
            *(uint4*)&Ah[sr * 40 + sk + g * 8] = qh;
            *(uint4*)&Al[sr * 40 + sk + g * 8] = qa;
        }
        {
            const size_t bo = (size_t)(n0 + sr) * K + k0 + sk;
            *(uint4*)&Bh[sr * 40 + sk]     = *(const uint4*)&BTh[bo];
            *(uint4*)&Bh[sr * 40 + sk + 8] = *(const uint4*)&BTh[bo + 8];
            *(uint4*)&Bl[sr * 40 + sk]     = *(const uint4*)&BTl[bo];
            *(uint4*)&Bl[sr * 40 + sk + 8] = *(const uint4*)&BTl[bo + 8];
        }
        __syncthreads();

        frag8 afh[4], afl[4], bfh[4], bfl[4];
        #pragma unroll
        for (int i = 0; i < 4; i++) {
            const int ar = wm + i * 16 + fr;
            afh[i] = *(frag8*)&Ah[ar * 40 + fq * 8];
            afl[i] = *(frag8*)&Al[ar * 40 + fq * 8];
        }
        #pragma unroll
        for (int j = 0; j < 4; j++) {
            const int br = wn + j * 16 + fr;
            bfh[j] = *(frag8*)&Bh[br * 40 + fq * 8];
            bfl[j] = *(frag8*)&Bl[br * 40 + fq * 8];
        }
        #pragma unroll
        for (int i = 0; i < 4; i++)
            #pragma unroll
            for (int j = 0; j < 4; j++) {
                acc[i][j] = __builtin_amdgcn_mfma_f32_16x16x32_bf16(afh[i], bfh[j], acc[i][j], 0, 0, 0);
                acc[i][j] = __builtin_amdgcn_mfma_f32_16x16x32_bf16(afh[i], bfl[j], acc[i][j], 0, 0, 0);
                acc[i][j] = __builtin_amdgcn_mfma_f32_16x16x32_bf16(afl[i], bfh[j], acc[i][j], 0, 0, 0);
            }
        __syncthreads();
    }

    float bv[4] = {0.f, 0.f, 0.f, 0.f};
    if (bias != nullptr)
        #pragma unroll
        for (int j = 0; j < 4; j++) bv[j] = bias[n0 + wn + j * 16 + fr];
    #pragma unroll
    for (int i = 0; i < 4; i++)
        #pragma unroll
        for (int j = 0; j < 4; j++) {
            const int col = n0 + wn + j * 16 + fr;
            #pragma unroll
            for (int r = 0; r < 4; r++) {
                const int row = m0 + wm + i * 16 + fq * 4 + r;
                const size_t off = (size_t)row * N + col;
                float c = acc[i][j][r] + bv[j];
                if (EPI == EPI_GELU)      c = gelu_f(c);
                else if (EPI == EPI_ADDS) c = c + 0.1f * bf2f(Xr[off]);
                C[off] = c;
            }
        }
}

// ---------------------------------------------------------------------------
// 1-pass bf16 GEMM (Phase A). A bf16 row-major [M,K] (or ACONCAT fp32 x|h),
// BT bf16 [N,K]. Epilogues write bf16 rm and/or col-major [N*M] copies.
// ---------------------------------------------------------------------------
template<int ACONCAT, int BEP>
__global__ __launch_bounds__(256)
void bgemm_k(const void* Av, const float* A2f, const ushort_t* __restrict__ BTh,
             const float* __restrict__ bias, const ushort_t* __restrict__ GpIn,
             ushort_t* Crm, ushort_t* Cct, ushort_t* GpOut,
             int M, int N, int K)
{
    __shared__ ushort_t Ah[128 * 40];
    __shared__ ushort_t Bh[128 * 40];
    const int tid = threadIdx.x;
    const int m0 = blockIdx.x * 128, n0 = blockIdx.y * 128;
    const int lane = tid & 63, w = tid >> 6;
    const int wm = (w & 1) * 64, wn = (w >> 1) * 64;
    const int fr = lane & 15, fq = lane >> 4;
    const int sr = tid >> 1;
    const int sk = (tid & 1) * 16;

    f32x4 acc[4][4];
    #pragma unroll
    for (int i = 0; i < 4; i++)
        #pragma unroll
        for (int j = 0; j < 4; j++) acc[i][j] = (f32x4){0.f, 0.f, 0.f, 0.f};

    for (int k0 = 0; k0 < K; k0 += 32) {
        if (ACONCAT) {
            const float* A = (const float*)Av;
            #pragma unroll
            for (int g = 0; g < 2; g++) {
                uint_t ph[4];
                #pragma unroll
                for (int c = 0; c < 2; c++) {
                    const int ak = k0 + sk + g * 8 + c * 4;
                    const float* ap = (ak < 256) ? (A + (size_t)(m0 + sr) * 256 + ak)
                                                 : (A2f + (size_t)(m0 + sr) * 256 + (ak - 256));
                    float4 v = *(const float4*)ap;
                    ph[c*2]   = (uint_t)cvt_rne(v.x) | ((uint_t)cvt_rne(v.y) << 16);
                    ph[c*2+1] = (uint_t)cvt_rne(v.z) | ((uint_t)cvt_rne(v.w) << 16);
                }
                uint4 q; q.x = ph[0]; q.y = ph[1]; q.z = ph[2]; q.w = ph[3];
                *(uint4*)&Ah[sr * 40 + sk + g * 8] = q;
            }
        } else {
            const ushort_t* A = (const ushort_t*)Av;
            const size_t ao = (size_t)(m0 + sr) * K + k0 + sk;
            *(uint4*)&Ah[sr * 40 + sk]     = *(const uint4*)&A[ao];
            *(uint4*)&Ah[sr * 40 + sk + 8] = *(const uint4*)&A[ao + 8];
        }
        {
            const size_t bo = (size_t)(n0 + sr) * K + k0 + sk;
            *(uint4*)&Bh[sr * 40 + sk]     = *(const uint4*)&BTh[bo];
            *(uint4*)&Bh[sr * 40 + sk + 8] = *(const uint4*)&BTh[bo + 8];
        }
        __syncthreads();

        frag8 af[4], bf[4];
        #pragma unroll
        for (int i = 0; i < 4; i++) af[i] = *(frag8*)&Ah[(wm + i * 16 + fr) * 40 + fq * 8];
        #pragma unroll
        for (int j = 0; j < 4; j++) bf[j] = *(frag8*)&Bh[(wn + j * 16 + fr) * 40 + fq * 8];
        #pragma unroll
        for (int i = 0; i < 4; i++)
            #pragma unroll
            for (int j = 0; j < 4; j++)
                acc[i][j] = __builtin_amdgcn_mfma_f32_16x16x32_bf16(af[i], bf[j], acc[i][j], 0, 0, 0);
        __syncthreads();
    }

    float bv[4] = {0.f, 0.f, 0.f, 0.f};
    if (bias != nullptr)
        #pragma unroll
        for (int j = 0; j < 4; j++) bv[j] = bias[n0 + wn + j * 16 + fr];
    #pragma unroll
    for (int i = 0; i < 4; i++)
        #pragma unroll
        for (int j = 0; j < 4; j++) {
            const int col = n0 + wn + j * 16 + fr;
            const int rowb = m0 + wm + i * 16 + fq * 4;
            float v[4];
            #pragma unroll
            for (int r = 0; r < 4; r++) v[r] = acc[i][j][r] + bv[j];
            if (BEP == BEP_A1) {
                ushort_t gc[4];
                #pragma unroll
                for (int r = 0; r < 4; r++) {
                    float g = gelu_f(v[r]);
                    gc[r] = cvt_rne(g);
                    Crm[(size_t)(rowb + r) * N + col] = gc[r];
                    GpOut[(size_t)(rowb + r) * N + col] = cvt_rne(dgelu_f(v[r]));
                }
                uint_t p0 = (uint_t)gc[0] | ((uint_t)gc[1] << 16);
                uint_t p1 = (uint_t)gc[2] | ((uint_t)gc[3] << 16);
                *(uint2*)&Cct[(size_t)col * M + rowb] = (uint2){p0, p1};
            } else if (BEP == BEP_DAT) {
                ushort_t dc[4];
                #pragma unroll
                for (int r = 0; r < 4; r++)
                    dc[r] = cvt_rne(v[r] * bf2f(GpIn[(size_t)(rowb + r) * N + col]));
                uint_t p0 = (uint_t)dc[0] | ((uint_t)dc[1] << 16);
                uint_t p1 = (uint_t)dc[2] | ((uint_t)dc[3] << 16);
                *(uint2*)&Cct[(size_t)col * M + rowb] = (uint2){p0, p1};
            } else {
                ushort_t cc[4];
                #pragma unroll
                for (int r = 0; r < 4; r++) {
                    cc[r] = cvt_rne(v[r]);
                    Crm[(size_t)(rowb + r) * N + col] = cc[r];
                }
                if (BEP == BEP_PT) {
                    uint_t p0 = (uint_t)cc[0] | ((uint_t)cc[1] << 16);
                    uint_t p1 = (uint_t)cc[2] | ((uint_t)cc[3] << 16);
                    *(uint2*)&Cct[(size_t)col * M + rowb] = (uint2){p0, p1};
                }
            }
        }
}

// ---------------------------------------------------------------------------
// Weight-grad: C[M,N] += AT[M,:]·BT[N,:] over split-K chunk. Both k-major bf16.
// ---------------------------------------------------------------------------
__global__ __launch_bounds__(256)
void wgrad_k(const ushort_t* __restrict__ AT, const ushort_t* __restrict__ BTt,
             float* C, int M, int N, int KA, int kofsA, int KB, int kofsB, int KC)
{
    __shared__ ushort_t Ah[128 * 40];
    __shared__ ushort_t Bh[128 * 40];
    const int tid = threadIdx.x;
    const int m0 = blockIdx.x * 128, n0 = blockIdx.y * 128;
    const int kbA = kofsA + blockIdx.z * KC;
    const int kbB = kofsB + blockIdx.z * KC;
    const int lane = tid & 63, w = tid >> 6;
    const int wm = (w & 1) * 64, wn = (w >> 1) * 64;
    const int fr = lane & 15, fq = lane >> 4;
    const int sr = tid >> 1;
    const int sk = (tid & 1) * 16;

    f32x4 acc[4][4];
    #pragma unroll
    for (int i = 0; i < 4; i++)
        #pragma unroll
        for (int j = 0; j < 4; j++) acc[i][j] = (f32x4){0.f, 0.f, 0.f, 0.f};

    for (int k0 = 0; k0 < KC; k0 += 32) {
        const size_t ao = (size_t)(m0 + sr) * KA + kbA + k0 + sk;
        *(uint4*)&Ah[sr * 40 + sk]     = *(const uint4*)&AT[ao];
        *(uint4*)&Ah[sr * 40 + sk + 8] = *(const uint4*)&AT[ao + 8];
        const size_t bo = (size_t)(n0 + sr) * KB + kbB + k0 + sk;
        *(uint4*)&Bh[sr * 40 + sk]     = *(const uint4*)&BTt[bo];
        *(uint4*)&Bh[sr * 40 + sk + 8] = *(const uint4*)&BTt[bo + 8];
        __syncthreads();

        frag8 af[4], bf[4];
        #pragma unroll
        for (int i = 0; i < 4; i++) af[i] = *(frag8*)&Ah[(wm + i * 16 + fr) * 40 + fq * 8];
        #pragma unroll
        for (int j = 0; j < 4; j++) bf[j] = *(frag8*)&Bh[(wn + j * 16 + fr) * 40 + fq * 8];
        #pragma unroll
        for (int i = 0; i < 4; i++)
            #pragma unroll
            for (int j = 0; j < 4; j++)
                acc[i][j] = __builtin_amdgcn_mfma_f32_16x16x32_bf16(af[i], bf[j], acc[i][j], 0, 0, 0);
        __syncthreads();
    }
    #pragma unroll
    for (int i = 0; i < 4; i++)
        #pragma unroll
        for (int j = 0; j < 4; j++) {
            const int col = n0 + wn + j * 16 + fr;
            #pragma unroll
            for (int r = 0; r < 4; r++) {
                const int row = m0 + wm + i * 16 + fq * 4 + r;
                atomicAdd(&C[(size_t)row * N + col], acc[i][j][r]);
            }
        }
}

// row-sums of col-major bf16 T [N, cols] -> db[n] (+= across chunks)
__global__ __launch_bounds__(256)
void colsumT_k(const ushort_t* __restrict__ T, float* db, int LD, int cols)
{
    const int n = blockIdx.x * 4 + (threadIdx.x >> 6);
    const int lane = threadIdx.x & 63;
    const ushort_t* row = T + (size_t)n * LD;
    float s = 0.f;
    for (int c = lane * 8; c < cols; c += 512) {
        uint4 q = *(const uint4*)&row[c];
        uint_t u[4] = {q.x, q.y, q.z, q.w};
        #pragma unroll
        for (int t = 0; t < 4; t++) {
            s += bf2f((ushort_t)(u[t] & 0xFFFF));
            s += bf2f((ushort_t)(u[t] >> 16));
        }
    }
    #pragma unroll
    for (int o = 32; o > 0; o >>= 1) s += __shfl_xor(s, o);
    if (lane == 0) atomicAdd(&db[n], s);
}

// LayerNorm fwd + dL/dr0, bf16 in/out (dr0 may alias r0)
__global__ __launch_bounds__(256)
void ln_bf_k(const ushort_t* r0, const ushort_t* __restrict__ phi,
             const float* __restrict__ gamma, const float* __restrict__ beta,
             ushort_t* recon, ushort_t* dr0)
{
    const int lane = threadIdx.x & 63;
    const int wv = threadIdx.x >> 6;
    const int row = blockIdx.x * 4 + wv;
    const size_t base = (size_t)row * U_N + (lane << 2);

    uint2 xu = *(const uint2*)(r0 + base);
    uint2 pu = *(const uint2*)(phi + base);
    float xs[4] = { bf2f((ushort_t)(xu.x & 0xFFFF)), bf2f((ushort_t)(xu.x >> 16)),
                    bf2f((ushort_t)(xu.y & 0xFFFF)), bf2f((ushort_t)(xu.y >> 16)) };
    float ps[4] = { bf2f((ushort_t)(pu.x & 0xFFFF)), bf2f((ushort_t)(pu.x >> 16)),
                    bf2f((ushort_t)(pu.y & 0xFFFF)), bf2f((ushort_t)(pu.y >> 16)) };
    float s = xs[0] + xs[1] + xs[2] + xs[3];
    float sq = xs[0]*xs[0] + xs[1]*xs[1] + xs[2]*xs[2] + xs[3]*xs[3];
    #pragma unroll
    for (int o = 32; o > 0; o >>= 1) { s += __shfl_xor(s, o); sq += __shfl_xor(sq, o); }
    const float m   = s * (1.0f / U_N);
    const float var = sq * (1.0f / U_N) - m * m;
    const float inv = rsqrtf(var + EPS_C);

    float4 gv = *(const float4*)(gamma + (lane << 2));
    float4 bvv = *(const float4*)(beta + (lane << 2));
    float gs[4] = {gv.x, gv.y, gv.z, gv.w};
    float bs[4] = {bvv.x, bvv.y, bvv.z, bvv.w};
    float rh[4], dh[4], rc[4];
    float s1 = 0.f, s2 = 0.f;
    const float gscale = 2.0f / ((float)B_N * (float)U_N);
    #pragma unroll
    for (int j = 0; j < 4; j++) {
        rh[j] = (xs[j] - m) * inv;
        rc[j] = rh[j] * gs[j] + bs[j];
        float g2 = gscale * (rc[j] - ps[j]);
        dh[j] = g2 * gs[j];
        s1 += dh[j];
        s2 += dh[j] * rh[j];
    }
    #pragma unroll
    for (int o = 32; o > 0; o >>= 1) { s1 += __shfl_xor(s1, o); s2 += __shfl_xor(s2, o); }
    const float mu1 = s1 * (1.0f / U_N);
    const float mu2 = s2 * (1.0f / U_N);
    ushort_t oc[4], dc[4];
    #pragma unroll
    for (int j = 0; j < 4; j++) {
        oc[j] = cvt_rne(rc[j]);
        dc[j] = cvt_rne(inv * (dh[j] - mu1 - rh[j] * mu2));
    }
    *(uint2*)(recon + base) = (uint2){ (uint_t)oc[0] | ((uint_t)oc[1] << 16),
                                       (uint_t)oc[2] | ((uint_t)oc[3] << 16) };
    *(uint2*)(dr0 + base)   = (uint2){ (uint_t)dc[0] | ((uint_t)dc[1] << 16),
                                       (uint_t)dc[2] | ((uint_t)dc[3] << 16) };
}

// transpose + split: W [R,C] fp32 -> Th (+Tl if HASL) [C,R]
template<int HASL>
__global__ __launch_bounds__(256)
void tsplit_k(const float* __restrict__ W, ushort_t* __restrict__ Th,
              ushort_t* __restrict__ Tl, int R, int C)
{
    __shared__ float t[64][65];
    const int tid = threadIdx.x;
    const int R0 = blockIdx.x * 64, C0 = blockIdx.y * 64;
    const int c = tid & 63, rb = (tid >> 6) * 16;
    for (int i = 0; i < 16; i++)
        t[rb + i][c] = W[(size_t)(R0 + rb + i) * C + C0 + c];
    __syncthreads();
    const int orr = tid & 63, ob = (tid >> 6) * 16;
    for (int i = 0; i < 16; i++) {
        const int oc = ob + i;
        ushort_t h, l;
        splitf(t[orr][oc], h, l);
        Th[(size_t)(C0 + oc) * R + R0 + orr] = h;
        if (HASL) Tl[(size_t)(C0 + oc) * R + R0 + orr] = l;
    }
}

// transpose + SGD update + split (hi+lo)
__global__ __launch_bounds__(256)
void tupd_k(const float* __restrict__ W, const float* __restrict__ dW,
            ushort_t* __restrict__ Th, ushort_t* __restrict__ Tl, int R, int C)
{
    __shared__ float t[64][65];
    const int tid = threadIdx.x;
    const int R0 = blockIdx.x * 64, C0 = blockIdx.y * 64;
    const int c = tid & 63, rb = (tid >> 6) * 16;
    for (int i = 0; i < 16; i++) {
        const size_t o = (size_t)(R0 + rb + i) * C + C0 + c;
        t[rb + i][c] = W[o] - LR_C * dW[o];
    }
    __syncthreads();
    const int orr = tid & 63, ob = (tid >> 6) * 16;
    for (int i = 0; i < 16; i++) {
        const int oc = ob + i;
        ushort_t h, l;
        splitf(t[orr][oc], h, l);
        Th[(size_t)(C0 + oc) * R + R0 + orr] = h;
        Tl[(size_t)(C0 + oc) * R + R0 + orr] = l;
    }
}

// elementwise hi-plane convert (no transpose)
__global__ __launch_bounds__(256)
void scvt_k(const float* __restrict__ W, ushort_t* __restrict__ Th, int n4)
{
    const int i = blockIdx.x * 256 + threadIdx.x;
    if (i >= n4) return;
    float4 v = *(const float4*)(W + (size_t)i * 4);
    uint2 ph;
    ph.x = (uint_t)cvt_rne(v.x) | ((uint_t)cvt_rne(v.y) << 16);
    ph.y = (uint_t)cvt_rne(v.z) | ((uint_t)cvt_rne(v.w) << 16);
    *(uint2*)&Th[(size_t)i * 4] = ph;
}

__global__ __launch_bounds__(256)
void bupd_k(const float* __restrict__ b1, const float* __restrict__ db1,
            const float* __restrict__ b2, const float* __restrict__ db2,
            float* __restrict__ b1u, float* __restrict__ b2u)
{
    const int i = blockIdx.x * 256 + threadIdx.x;
    if (i < H_N) b1u[i] = b1[i] - LR_C * db1[i];
    else if (i < H_N + U_N) b2u[i - H_N] = b2[i - H_N] - LR_C * db2[i - H_N];
}

extern "C" void kernel_launch(void* const* d_in, const int* in_sizes, int n_in,
                              void* d_out, int out_size, void* d_ws, size_t ws_size,
                              hipStream_t stream)
{
    const float* x      = (const float*)d_in[0];
    const float* h_prev = (const float*)d_in[1];
    const float* W_phi  = (const float*)d_in[2];
    const float* b_phi  = (const float*)d_in[3];
    const float* W_psi  = (const float*)d_in[4];
    const float* b_psi  = (const float*)d_in[5];
    const float* W1     = (const float*)d_in[6];
    const float* b1     = (const float*)d_in[7];
    const float* W2     = (const float*)d_in[8];
    const float* b2     = (const float*)d_in[9];
    const float* W_g    = (const float*)d_in[10];
    const float* g_bias = (const float*)d_in[11];
    const float* gamma  = (const float*)d_in[12];
    const float* beta   = (const float*)d_in[13];
    const float* W_h    = (const float*)d_in[14];
    const float* h_bias = (const float*)d_in[15];
    float* out = (float*)d_out;

    const size_t BU = (size_t)B_N * U_N;
    const size_t UH = (size_t)U_N * H_N;

    // ---- fixed allocations ----
    float* ws  = (float*)d_ws;
    float* dW1 = ws;                      // [U,H]
    float* db1 = dW1 + UH;                // [H]
    float* dW2 = db1 + H_N;               // [H,U]
    float* db2 = dW2 + UH;                // [U]
    float* b1u = db2 + U_N;
    float* b2u = b1u + H_N;
    ushort_t* us = (ushort_t*)(((uintptr_t)(b2u + U_N) + 15) & ~(uintptr_t)15);
    // weight planes
    ushort_t* WphiT_h = us;                   // [U,512]
    ushort_t* WpsiT_h = WphiT_h + 131072;     ushort_t* WpsiT_l = WpsiT_h + 131072;
    ushort_t* W1T_h   = WpsiT_l + 131072;     // [H,U]
    ushort_t* W2T_h   = W1T_h + 262144;       // [U,H]
    ushort_t* W2s_h   = W2T_h + 262144;       // W2 row-major [H,U]
    ushort_t* Wgs_h   = W2s_h + 262144;       // Wg row-major
    ushort_t* WgT_h   = Wgs_h + 65536;
    ushort_t* W1uT_h  = WgT_h + 65536;        ushort_t* W1uT_l = W1uT_h + 262144;
    ushort_t* W2uT_h  = W1uT_l + 262144;      ushort_t* W2uT_l = W2uT_h + 262144;
    ushort_t* WhT_h   = W2uT_l + 262144;      ushort_t* WhT_l  = WhT_h + 65536;
    // persistent bf16 activations
    ushort_t* phi_bf  = WhT_l + 65536;        // [B,U]
    ushort_t* phiT_bf = phi_bf + BU;          // [U,B]
    ushort_t* recon_bf= phiT_bf + BU;         // [B,U]
    ushort_t* chunk0  = recon_bf + BU;        // chunk region start
    const size_t P_bytes = (size_t)((char*)chunk0 - (char*)d_ws);

    // ---- chunk sizing ----
    // Phase A per-chunk bytes: Bc*(4H + 4U)*2 = Bc*10240; Phase C: Bc*6144 (f32)
    int GA = 2;
    while (GA < 256 && P_bytes + (size_t)(B_N / GA) * 10240 + (1 << 20) > ws_size) GA *= 2;
    size_t region = (size_t)(B_N / GA) * 10240;
    int GC = 1;
    while (GC < 256) {
        size_t cC = (size_t)(B_N / GC) * 6144;
        size_t r = cC > region ? cC : region;
        if (P_bytes + r + (1 << 20) <= ws_size) { region = r; break; }
        GC *= 2;
    }
    const int BcA = B_N / GA;
    const int BcC = B_N / GC;
    const int KC = (BcA >= 8192) ? 512 : ((BcA >= 1024) ? BcA / 16 : BcA);
    const int Z  = BcA / KC;

    // Phase A chunk buffers (bf16)
    ushort_t* g1  = chunk0;                       // [BcA,H]
    ushort_t* gp  = g1  + (size_t)BcA * H_N;      // [BcA,H]
    ushort_t* g1T = gp  + (size_t)BcA * H_N;      // [H,BcA]
    ushort_t* daT = g1T + (size_t)BcA * H_N;      // [H,BcA]
    ushort_t* e_b = daT + (size_t)BcA * H_N;      // [BcA,U]
    ushort_t* r0b = e_b + (size_t)BcA * U_N;      // [BcA,U]  (r0 -> dr0)
    ushort_t* deb = r0b + (size_t)BcA * U_N;      // [BcA,U]
    ushort_t* deT = deb + (size_t)BcA * U_N;      // [U,BcA]
    // Phase C chunk buffers (fp32, overlay same region)
    float* psi_f  = (float*)chunk0;               // [BcC,U]
    float* h2_f   = psi_f + (size_t)BcC * U_N;    // [BcC,H]
    float* feat_f = h2_f + (size_t)BcC * H_N;     // [BcC,U]

    hipMemsetAsync(dW1, 0, (2 * UH + H_N + U_N) * sizeof(float), stream);

    dim3 blk(256);
    // weight prep
    tsplit_k<0><<<dim3(8, 4),  blk, 0, stream>>>(W_phi, WphiT_h, nullptr, 512, 256);
    tsplit_k<1><<<dim3(8, 4),  blk, 0, stream>>>(W_psi, WpsiT_h, WpsiT_l, 512, 256);
    tsplit_k<0><<<dim3(4, 16), blk, 0, stream>>>(W1, W1T_h, nullptr, 256, 1024);
    tsplit_k<0><<<dim3(16, 4), blk, 0, stream>>>(W2, W2T_h, nullptr, 1024, 256);
    tsplit_k<0><<<dim3(4, 4),  blk, 0, stream>>>(W_g, WgT_h, nullptr, 256, 256);
    tsplit_k<1><<<dim3(4, 4),  blk, 0, stream>>>(W_h, WhT_h, WhT_l, 256, 256);
    scvt_k<<<dim3(256), blk, 0, stream>>>(W2, W2s_h, 65536);
    scvt_k<<<dim3(64),  blk, 0, stream>>>(W_g, Wgs_h, 16384);

    // phi = [x|h_prev] @ W_phi + b_phi  (1-pass, bf16 out rm + T)
    bgemm_k<1, BEP_PT><<<dim3(B_N / 128, 2), blk, 0, stream>>>(
        x, h_prev, WphiT_h, b_phi, nullptr, phi_bf, phiT_bf, nullptr, B_N, U_N, 512);

    // ---- Phase A: inner fwd+bwd, 1-pass bf16, chunked ----
    for (int c = 0; c < GA; c++) {
        const size_t off = (size_t)c * BcA;
        const ushort_t* phic = phi_bf + off * U_N;
        // a1 = phi@W1+b1 -> g1(gelu) rm, gp(dgelu) rm, g1T ct
        bgemm_k<0, BEP_A1><<<dim3(BcA / 128, 8), blk, 0, stream>>>(
            phic, nullptr, W1T_h, b1, nullptr, g1, g1T, gp, BcA, H_N, U_N);
        // e = g1@W2 + b2
        bgemm_k<0, BEP_P><<<dim3(BcA / 128, 2), blk, 0, stream>>>(
            g1, nullptr, W2T_h, b2, nullptr, e_b, nullptr, nullptr, BcA, U_N, H_N);
        // r0 = e@Wg + g_bias
        bgemm_k<0, BEP_P><<<dim3(BcA / 128, 2), blk, 0, stream>>>(
            e_b, nullptr, WgT_h, g_bias, nullptr, r0b, nullptr, nullptr, BcA, U_N, U_N);
        // recon, dr0 (in-place over r0b)
        ln_bf_k<<<dim3(BcA / 4), blk, 0, stream>>>(r0b, phic, gamma, beta,
                                                   recon_bf + off * U_N, r0b);
        // de = dr0@Wg^T -> rm + T
        bgemm_k<0, BEP_PT><<<dim3(BcA / 128, 2), blk, 0, stream>>>(
            r0b, nullptr, Wgs_h, nullptr, nullptr, deb, deT, nullptr, BcA, U_N, U_N);
        // da = (de@W2^T)*gp -> daT only
        bgemm_k<0, BEP_DAT><<<dim3(BcA / 128, 8), blk, 0, stream>>>(
            deb, nullptr, W2s_h, nullptr, gp, nullptr, daT, nullptr, BcA, H_N, U_N);
        // dW2 += g1T·deT ; db2 += rowsum(deT)
        wgrad_k<<<dim3(8, 2, Z), blk, 0, stream>>>(g1T, deT, dW2, H_N, U_N,
                                                   BcA, 0, BcA, 0, KC);
        colsumT_k<<<dim3(U_N / 4), blk, 0, stream>>>(deT, db2, BcA, BcA);
        // dW1 += phiT·daT ; db1 += rowsum(daT)
        wgrad_k<<<dim3(2, 8, Z), blk, 0, stream>>>(phiT_bf, daT, dW1, U_N, H_N,
                                                   B_N, (int)off, BcA, 0, KC);
        colsumT_k<<<dim3(H_N / 4), blk, 0, stream>>>(daT, db1, BcA, BcA);
    }

    // ---- Phase B: updated params ----
    bupd_k<<<dim3(5), blk, 0, stream>>>(b1, db1, b2, db2, b1u, b2u);
    tupd_k<<<dim3(4, 16), blk, 0, stream>>>(W1, dW1, W1uT_h, W1uT_l, 256, 1024);
    tupd_k<<<dim3(16, 4), blk, 0, stream>>>(W2, dW2, W2uT_h, W2uT_l, 1024, 256);

    // ---- Phase C: 3-pass forward ----
    for (int c = 0; c < GC; c++) {
        const size_t off = (size_t)c * BcC;
        mgemm_k<1, 0, EPI_NONE><<<dim3(BcC / 128, 2), blk, 0, stream>>>(
            x + off * 256, h_prev + off * U_N, WpsiT_h, WpsiT_l, b_psi, nullptr,
            psi_f, BcC, U_N, 512);
        mgemm_k<0, 0, EPI_GELU><<<dim3(BcC / 128, 8), blk, 0, stream>>>(
            psi_f, nullptr, W1uT_h, W1uT_l, b1u, nullptr, h2_f, BcC, H_N, U_N);
        mgemm_k<0, 0, EPI_ADDS><<<dim3(BcC / 128, 2), blk, 0, stream>>>(
            h2_f, nullptr, W2uT_h, W2uT_l, b2u, recon_bf + off * U_N, feat_f, BcC, U_N, H_N);
        mgemm_k<0, 0, EPI_NONE><<<dim3(BcC / 128, 2), blk, 0, stream>>>(
            feat_f, nullptr, WhT_h, WhT_l, h_bias, nullptr, out + off * U_N, BcC, U_N, U_N);
    }
}